// Round 8
// baseline (410.383 us; speedup 1.0000x reference)
//
#include <hip/hip_runtime.h>

// B=8, S=512, DM=1024, H=16, D=64
using short8 = __attribute__((ext_vector_type(8))) short;
using f32x4  = __attribute__((ext_vector_type(4))) float;
typedef unsigned short u16x4 __attribute__((ext_vector_type(4)));
typedef unsigned short u16x8 __attribute__((ext_vector_type(8)));

__device__ __forceinline__ unsigned short f2bf(float x) {
    union { float f; unsigned u; } v; v.f = x;
    unsigned u = v.u;
    unsigned r = (u + 0x7fffu + ((u >> 16) & 1u)) >> 16;   // RNE
    return (unsigned short)r;
}
__device__ __forceinline__ float bf2f(unsigned short h) {
    union { unsigned u; float f; } v; v.u = ((unsigned)h) << 16;
    return v.f;
}

__device__ __forceinline__ void async16(const void* g, void* l) {
    __builtin_amdgcn_global_load_lds(
        (const __attribute__((address_space(1))) void*)g,
        (__attribute__((address_space(3))) void*)l, 16, 0, 0);
}

// swizzled LDS b128 read: byte = row*stride + (colbyte ^ ((row&7)<<4))
__device__ __forceinline__ short8 lds_swz8(const unsigned short* base, int row,
                                           int colbyte, int stride) {
    const char* p = (const char*)base + row * stride + (colbyte ^ ((row & 7) << 4));
    return *(const short8*)p;
}

// ---------------------------------------------------------------------------
// fp32 -> bf16 converter, QKV (3x4M) + weights (4x1M) in one launch
// ---------------------------------------------------------------------------
__global__ __launch_bounds__(256) void cvt_all(
    const float* __restrict__ q, const float* __restrict__ k, const float* __restrict__ v,
    const float* __restrict__ wq, const float* __restrict__ wk,
    const float* __restrict__ wv, const float* __restrict__ wo,
    unsigned short* __restrict__ dstA, unsigned short* __restrict__ dstW)
{
    int bx = blockIdx.x;
    const float* src;
    unsigned short* o;
    size_t i;
    if (bx < 6144) {
        int z = bx >> 11;
        src = (z == 0) ? q : ((z == 1) ? k : v);
        o = dstA + (size_t)z * 4194304;
        i = ((size_t)(bx & 2047) * 256 + threadIdx.x) * 8;
    } else {
        int z = (bx - 6144) >> 9;
        src = (z == 0) ? wq : ((z == 1) ? wk : ((z == 2) ? wv : wo));
        o = dstW + (size_t)z * 1048576;
        i = ((size_t)((bx - 6144) & 511) * 256 + threadIdx.x) * 8;
    }
    float4 a = *(const float4*)(src + i);
    float4 b = *(const float4*)(src + i + 4);
    ushort4 lo, hi;
    lo.x = f2bf(a.x); lo.y = f2bf(a.y); lo.z = f2bf(a.z); lo.w = f2bf(a.w);
    hi.x = f2bf(b.x); hi.y = f2bf(b.y); hi.z = f2bf(b.z); hi.w = f2bf(b.w);
    *(ushort4*)(o + i) = lo;
    *(ushort4*)(o + i + 4) = hi;
}

// ---------------------------------------------------------------------------
// feature precompute: F[b][q>>2][k][r][f] = {dist,spk,disc,cooc}  (bf16)
// Raw 4-feature store (16.75 MB) instead of 16 head-projected bf16 (64 MB);
// per-head 1x1 conv folded into attn (head-uniform scalars there).
// One lane's (q-quad, k): 16 bf16 = 32B contiguous -> 2KB/wave coalesced.
// ---------------------------------------------------------------------------
__global__ __launch_bounds__(256) void feat_kernel(
    const int* __restrict__ dist_adj, const float* __restrict__ spk,
    const int* __restrict__ disc_adj, const int* __restrict__ cooc_adj,
    const float* __restrict__ dist_emb, const float* __restrict__ disc_emb,
    const float* __restrict__ cooc_emb, unsigned short* __restrict__ F)
{
    __shared__ float s_dist[1023];
    __shared__ float s_disc[17];
    __shared__ float s_cooc[6];
    int tid = threadIdx.x;
    for (int i = tid; i < 1023; i += 256) s_dist[i] = dist_emb[i];
    if (tid < 17) s_disc[tid] = disc_emb[tid];
    if (tid < 6)  s_cooc[tid] = cooc_emb[tid];
    __syncthreads();

    // 2048 blocks: bx = b(3b) | qq(7b) | khalf(1b)
    int bx = blockIdx.x;
    int k  = (bx & 1) * 256 + tid;
    int qq = (bx >> 1) & 127;
    int b  = bx >> 8;

    size_t abase = ((size_t)b * 512 + qq * 4) * 512 + k;
    u16x8 oA, oB;
#pragma unroll
    for (int r = 0; r < 4; ++r) {
        size_t a = abase + (size_t)r * 512;
        int dd   = __builtin_nontemporal_load(dist_adj + a);
        float sp = __builtin_nontemporal_load(spk + a);
        int dc   = __builtin_nontemporal_load(disc_adj + a);
        int cc   = __builtin_nontemporal_load(cooc_adj + a);
        unsigned short f0 = f2bf(s_dist[dd]);
        unsigned short f1 = f2bf(sp);
        unsigned short f2 = f2bf(dc ? s_disc[dc] : 0.f);
        unsigned short f3 = f2bf(cc ? s_cooc[cc] : 0.f);
        if (r < 2) {
            oA[r * 4 + 0] = f0; oA[r * 4 + 1] = f1; oA[r * 4 + 2] = f2; oA[r * 4 + 3] = f3;
        } else {
            oB[(r - 2) * 4 + 0] = f0; oB[(r - 2) * 4 + 1] = f1;
            oB[(r - 2) * 4 + 2] = f2; oB[(r - 2) * 4 + 3] = f3;
        }
    }
    // cached stores: attn re-reads 16x (per-XCD F slice 2.1 MB -> L2-resident)
    unsigned short* fb = F + (((size_t)b * 128 + qq) * 512 + k) * 16;
    *(u16x8*)(fb)     = oA;
    *(u16x8*)(fb + 8) = oB;
}

// ---------------------------------------------------------------------------
// bf16 GEMM, m97 structure: C[m,n] = sum_k A[m,k]*W[n,k] + bias[n]
// OMODE 0: bf16 split-head [b,h,s,d]; OMODE 1: fp32 [m][1024]
// ---------------------------------------------------------------------------
template<int OMODE>
__device__ __forceinline__ void gemm_bf16_body(
    const unsigned short* __restrict__ A, const unsigned short* __restrict__ W,
    const float* __restrict__ bias, void* __restrict__ outp, int m0, int n0)
{
    __shared__ __align__(16) unsigned short As[128 * 32];   // row-major, NO pad
    __shared__ __align__(16) unsigned short Bs[128 * 32];
    int tid = threadIdx.x;
    int lane = tid & 63, wid = tid >> 6;
    int wx = wid & 1, wy = wid >> 1;
    int lanelo = lane & 15, hi8 = (lane >> 4) * 8;
    int rowc = lane >> 2;          // row within 16-row chunk
    int colc = (lane & 3) * 8;     // k-offset (elems) within row

    f32x4 acc[4][4];
#pragma unroll
    for (int i = 0; i < 4; ++i)
#pragma unroll
        for (int j = 0; j < 4; ++j) {
            acc[i][j][0] = 0.f; acc[i][j][1] = 0.f; acc[i][j][2] = 0.f; acc[i][j][3] = 0.f;
        }

    for (int kk = 0; kk < 32; ++kk) {
        int k0 = kk * 32;
        __syncthreads();
#pragma unroll
        for (int p = 0; p < 2; ++p) {
            int c = 2 * wid + p;           // chunk 0..7
            int row = c * 16 + rowc;
            async16(A + (size_t)(m0 + row) * 1024 + k0 + colc, As + c * 512);
        }
#pragma unroll
        for (int p = 0; p < 2; ++p) {
            int c = 2 * wid + p;
            int row = c * 16 + rowc;
            async16(W + (size_t)(n0 + row) * 1024 + k0 + colc, Bs + c * 512);
        }
        __syncthreads();

        short8 af[4], bfr[4];
#pragma unroll
        for (int i = 0; i < 4; ++i)
            af[i] = *(const short8*)(As + (wy*64 + i*16 + lanelo) * 32 + hi8);
#pragma unroll
        for (int j = 0; j < 4; ++j)
            bfr[j] = *(const short8*)(Bs + (wx*64 + j*16 + lanelo) * 32 + hi8);
#pragma unroll
        for (int i = 0; i < 4; ++i)
#pragma unroll
            for (int j = 0; j < 4; ++j)
                acc[i][j] = __builtin_amdgcn_mfma_f32_16x16x32_bf16(af[i], bfr[j], acc[i][j], 0, 0, 0);
    }

    float bia[4];
#pragma unroll
    for (int j = 0; j < 4; ++j) bia[j] = bias[n0 + wx*64 + j*16 + lanelo];
#pragma unroll
    for (int i = 0; i < 4; ++i) {
        int mbase = m0 + wy*64 + i*16 + (lane >> 4) * 4;
#pragma unroll
        for (int j = 0; j < 4; ++j) {
            int n = n0 + wx*64 + j*16 + lanelo;
#pragma unroll
            for (int r = 0; r < 4; ++r) {
                int m = mbase + r;
                float val = acc[i][j][r] + bia[j];
                if (OMODE == 0) {
                    unsigned short* o = (unsigned short*)outp;
                    o[((size_t)((m >> 9) * 16 + (n >> 6)) * 512 + (m & 511)) * 64 + (n & 63)] = f2bf(val);
                } else {
                    float* o = (float*)outp;
                    o[(size_t)m * 1024 + n] = val;
                }
            }
        }
    }
}

// grid (32, 8, 3): x = m-tile, y = n-tile, z = tensor
__global__ __launch_bounds__(256) void gemm_qkv(
    const unsigned short* __restrict__ Abf, const unsigned short* __restrict__ Wbf,
    const float* __restrict__ bq, const float* __restrict__ bk, const float* __restrict__ bv,
    unsigned short* Qb, unsigned short* Kb, unsigned short* Vb)
{
    int z = blockIdx.z;
    const unsigned short* A = Abf + (size_t)z * 4194304;
    const unsigned short* W = Wbf + (size_t)z * 1048576;
    const float* bias = (z == 0) ? bq : ((z == 1) ? bk : bv);
    unsigned short* o = (z == 0) ? Qb : ((z == 1) ? Kb : Vb);
    gemm_bf16_body<0>(A, W, bias, o, blockIdx.x * 128, blockIdx.y * 128);
}

__global__ __launch_bounds__(256) void gemm_proj(
    const unsigned short* __restrict__ xh, const unsigned short* __restrict__ Wo,
    const float* __restrict__ bo, float* __restrict__ out)
{
    gemm_bf16_body<1>(xh, Wo, bo, out, blockIdx.x * 128, blockIdx.y * 128);
}

// ---------------------------------------------------------------------------
// Transpose V: [b,h,s,d] bf16 -> Vt [b,h,d,s] bf16 (coalesced both sides)
// ---------------------------------------------------------------------------
__global__ __launch_bounds__(256) void transpose_v(const unsigned short* __restrict__ Vb,
                                                   unsigned short* __restrict__ Vt)
{
    __shared__ __align__(16) unsigned short T[64][72];
    int tid = threadIdx.x;
    int s0 = blockIdx.x * 64;
    int bh = blockIdx.z * 16 + blockIdx.y;
#pragma unroll
    for (int p = 0; p < 2; ++p) {
        int c = p * 256 + tid;
        int row = c >> 3, kc = (c & 7) * 8;
        uint4 v = *(const uint4*)(Vb + ((size_t)bh * 512 + s0 + row) * 64 + kc);
        *(uint4*)&T[row][kc] = v;
    }
    __syncthreads();
#pragma unroll
    for (int p = 0; p < 2; ++p) {
        int c = p * 256 + tid;
        int d = c >> 3, sc = (c & 7) * 8;
        unsigned vv[4];
#pragma unroll
        for (int i = 0; i < 4; ++i) {
            unsigned lo = T[sc + 2*i][d];
            unsigned hi = T[sc + 2*i + 1][d];
            vv[i] = lo | (hi << 16);
        }
        uint4 o; o.x = vv[0]; o.y = vv[1]; o.z = vv[2]; o.w = vv[3];
        *(uint4*)(Vt + ((size_t)bh * 64 + d) * 512 + s0 + sc) = o;
    }
}

// ---------------------------------------------------------------------------
// Attention. bf16 raw-F loads (16B/j, whole kt-tile prefetched before the
// staging barrier, R6-proven structure); per-head 1x1 conv folded in.
// LDS arena (35840 B):
//   phase1: Qs[64][64]swz @0 (8K), Ks[128][64]swz @8192 (16K)
//   phase3: Vs[64][128]swz @0 (16K), Ps[4][16][136] @16384 (17408)
//   s_mask @33792 (2048)
// ---------------------------------------------------------------------------
__global__ __launch_bounds__(256, 2) void attn_kernel(
    const unsigned short* __restrict__ Qb, const unsigned short* __restrict__ Kb,
    const unsigned short* __restrict__ Vt, const unsigned short* __restrict__ F,
    const int* __restrict__ mask, const float* __restrict__ cw,
    const float* __restrict__ cb, const float* __restrict__ fcw,
    const float* __restrict__ fcb, float* __restrict__ attn_out,
    unsigned short* __restrict__ xh)
{
    __shared__ __align__(16) char smem[35840];
    unsigned short* Qs = (unsigned short*)smem;             // [64][64] swz
    unsigned short* Ks = (unsigned short*)(smem + 8192);    // [128][64] swz
    unsigned short* Vs = (unsigned short*)smem;             // [64][128] swz (phase3)
    unsigned short* Ps = (unsigned short*)(smem + 16384);   // [4][16][136]
    int* s_mask = (int*)(smem + 33792);

    int tid = threadIdx.x;
    int lane = tid & 63, w = tid >> 6;
    int lanelo = lane & 15, hi8 = (lane >> 4) * 8;
    int hi2 = lane >> 4;

    // XCD-aware decomposition: lin%8 = XCD; each XCD owns one b (16 heads)
    int lin = blockIdx.x;
    int xcd = lin & 7;
    int s   = lin >> 3;                 // 0..127
    int bh  = xcd * 16 + (s >> 3);
    int qt  = s & 7;
    int b   = bh >> 4, h = bh & 15;

    float qs  = cw[0] * 0.125f;
    float cw1 = cw[1];
    float cbv = cb[0];
    float w0 = fcw[h * 4 + 0], w1 = fcw[h * 4 + 1];
    float w2 = fcw[h * 4 + 2], w3 = fcw[h * 4 + 3];
    float fcb_h = fcb[h];

    s_mask[tid]       = mask[b * 512 + tid];
    s_mask[tid + 256] = mask[b * 512 + tid + 256];

    // ---- stage Q (8KB, swizzled source) ----
    int r8  = lane >> 3;                 // row within 8-row block
    int gs8 = (lane & 7) ^ r8;           // pre-swizzled 16B slot (128B rows)
#pragma unroll
    for (int p = 0; p < 2; ++p) {
        int row = p * 32 + w * 8 + r8;
        async16(Qb + ((size_t)bh * 512 + qt * 64 + row) * 64 + gs8 * 8,
                Qs + (p * 32 + w * 8) * 64);
    }
    __syncthreads();

    short8 aq[2];
    aq[0] = lds_swz8(Qs, w * 16 + lanelo, hi8 * 2, 128);
    aq[1] = lds_swz8(Qs, w * 16 + lanelo, 64 + hi8 * 2, 128);
    int qrow = qt * 64 + w * 16 + hi2 * 4;
    int qq   = qt * 16 + w * 4 + hi2;                 // q >> 2 for this lane's rows
    // F base for this lane's q-quad: ushort offset ((b*128+qq)*512 + k)*16
    const unsigned short* fbase = F + ((size_t)b * 128 + qq) * 512 * 16;

    float P[32][4];
#pragma unroll
    for (int kt = 0; kt < 4; ++kt) {
        // prefetch this kt-tile's F (16 bf16 = 2x16B per j); issued before the
        // staging barrier so latency hides under K staging (R6 structure)
        u16x8 fA[8], fB[8];
#pragma unroll
        for (int j = 0; j < 8; ++j) {
            const unsigned short* fp = fbase + (size_t)((kt * 8 + j) * 16 + lanelo) * 16;
            fA[j] = *(const u16x8*)(fp);
            fB[j] = *(const u16x8*)(fp + 8);
        }
        __syncthreads();                 // WAR: prev Ks reads done
        // ---- stage K tile (16KB, swizzled source) ----
#pragma unroll
        for (int p = 0; p < 4; ++p) {
            int row = p * 32 + w * 8 + r8;
            async16(Kb + ((size_t)bh * 512 + kt * 128 + row) * 64 + gs8 * 8,
                    Ks + (p * 32 + w * 8) * 64);
        }
        __syncthreads();
#pragma unroll
        for (int j = 0; j < 8; ++j) {
            short8 b0 = lds_swz8(Ks, j * 16 + lanelo, hi8 * 2, 128);
            short8 b1 = lds_swz8(Ks, j * 16 + lanelo, 64 + hi8 * 2, 128);
            f32x4 acc; acc[0] = 0.f; acc[1] = 0.f; acc[2] = 0.f; acc[3] = 0.f;
            acc = __builtin_amdgcn_mfma_f32_16x16x32_bf16(aq[0], b0, acc, 0, 0, 0);
            acc = __builtin_amdgcn_mfma_f32_16x16x32_bf16(aq[1], b1, acc, 0, 0, 0);
            int jj = kt * 8 + j;
            int kcol = jj * 16 + lanelo;
            int mk = s_mask[kcol];
#pragma unroll
            for (int r = 0; r < 4; ++r) {
                unsigned short e0, e1, e2, e3;
                if (r < 2) {
                    e0 = (unsigned short)fA[j][r*4+0]; e1 = (unsigned short)fA[j][r*4+1];
                    e2 = (unsigned short)fA[j][r*4+2]; e3 = (unsigned short)fA[j][r*4+3];
                } else {
                    e0 = (unsigned short)fB[j][(r-2)*4+0]; e1 = (unsigned short)fB[j][(r-2)*4+1];
                    e2 = (unsigned short)fB[j][(r-2)*4+2]; e3 = (unsigned short)fB[j][(r-2)*4+3];
                }
                float dot = w0 * bf2f(e0) + w1 * bf2f(e1) + w2 * bf2f(e2)
                          + w3 * bf2f(e3) + fcb_h;
                float gh = fmaxf(dot, 0.f) * cw1;
                float e = qs * acc[r] + gh + cbv;
                e = fmaxf(e, 0.f);
                P[jj][r] = mk ? __expf(e) : 0.f;
            }
        }
    }

    float inv[4];
#pragma unroll
    for (int r = 0; r < 4; ++r) {
        float s0 = 0.f;
#pragma unroll
        for (int jj = 0; jj < 32; ++jj) s0 += P[jj][r];
        s0 += __shfl_xor(s0, 1, 64);
        s0 += __shfl_xor(s0, 2, 64);
        s0 += __shfl_xor(s0, 4, 64);
        s0 += __shfl_xor(s0, 8, 64);
        inv[r] = 1.0f / s0;
    }

    // normalized P -> attn_out: scalar nt stores (16-lane group = 64B segment)
    {
        float* ap = attn_out + ((size_t)bh * 512 + qrow) * 512 + lanelo;
#pragma unroll
        for (int jj = 0; jj < 32; ++jj)
#pragma unroll
            for (int r = 0; r < 4; ++r)
                __builtin_nontemporal_store(P[jj][r] * inv[r],
                                            ap + (size_t)r * 512 + jj * 16);
    }

    // ---- PV in 4 chunks of K=128 ----
    f32x4 xacc[4];
#pragma unroll
    for (int jf = 0; jf < 4; ++jf) { xacc[jf][0]=0.f; xacc[jf][1]=0.f; xacc[jf][2]=0.f; xacc[jf][3]=0.f; }

    int r8v  = ((w & 1) * 4 + hi2) & 7;        // Vs row&7 for this lane's stage row
    int gs16 = (lane & 15) ^ r8v;              // pre-swizzled 16B slot (256B rows)
    unsigned short* Psw = Ps + w * 16 * 136;
#pragma unroll
    for (int c = 0; c < 4; ++c) {
        __syncthreads();                       // WAR (c=0: Qs/Ks dead; else prev reads)
        // stage Vt[:, c*128 +: 128] (16KB, swizzled source)
#pragma unroll
        for (int p = 0; p < 4; ++p) {
            int row = p * 16 + w * 4 + hi2;
            async16(Vt + ((size_t)bh * 64 + row) * 512 + c * 128 + gs16 * 8,
                    Vs + (p * 16 + w * 4) * 128);
        }
        // transpose this chunk of P into Ps (per-wave region)
#pragma unroll
        for (int jc = 0; jc < 8; ++jc) {
            int jj = c * 8 + jc;
#pragma unroll
            for (int r = 0; r < 4; ++r)
                Psw[(hi2 * 4 + r) * 136 + jc * 16 + lanelo] = f2bf(P[jj][r]);
        }
        __syncthreads();
#pragma unroll
        for (int ksub = 0; ksub < 4; ++ksub) {
            short8 ap8 = *(const short8*)(Psw + (size_t)lanelo * 136 + ksub * 32 + hi8);
#pragma unroll
            for (int jf = 0; jf < 4; ++jf) {
                short8 bv = lds_swz8(Vs, jf * 16 + lanelo, ksub * 64 + hi8 * 2, 256);
                xacc[jf] = __builtin_amdgcn_mfma_f32_16x16x32_bf16(ap8, bv, xacc[jf], 0, 0, 0);
            }
        }
    }

#pragma unroll
    for (int jf = 0; jf < 4; ++jf) {
        int d = jf * 16 + lanelo;
#pragma unroll
        for (int r = 0; r < 4; ++r) {
            float val = xacc[jf][r] * inv[r];
            xh[((size_t)b * 512 + qrow + r) * 1024 + h * 64 + d] = f2bf(val);
        }
    }
}

// ---------------------------------------------------------------------------
extern "C" void kernel_launch(void* const* d_in, const int* in_sizes, int n_in,
                              void* d_out, int out_size, void* d_ws, size_t ws_size,
                              hipStream_t stream) {
    (void)in_sizes; (void)n_in; (void)out_size; (void)ws_size;
    const float* query    = (const float*)d_in[0];
    const float* key      = (const float*)d_in[1];
    const float* value    = (const float*)d_in[2];
    const int*   dist_adj = (const int*)d_in[3];
    const float* spk      = (const float*)d_in[4];
    const int*   disc_adj = (const int*)d_in[5];
    const int*   cooc_adj = (const int*)d_in[6];
    const int*   maskp    = (const int*)d_in[7];
    const float* Wq = (const float*)d_in[8];  const float* bq = (const float*)d_in[9];
    const float* Wk = (const float*)d_in[10]; const float* bk = (const float*)d_in[11];
    const float* Wv = (const float*)d_in[12]; const float* bv = (const float*)d_in[13];
    const float* Wo = (const float*)d_in[14]; const float* bo = (const float*)d_in[15];
    const float* dist_emb = (const float*)d_in[16];
    const float* disc_emb = (const float*)d_in[17];
    const float* cooc_emb = (const float*)d_in[18];
    const float* fcw = (const float*)d_in[19];
    const float* fcb = (const float*)d_in[20];
    const float* cw  = (const float*)d_in[21];
    const float* cbp = (const float*)d_in[22];

    char* w = (char*)d_ws;
    unsigned short* Qb  = (unsigned short*)(w);                   //  8 MB
    unsigned short* Kb  = (unsigned short*)(w + 8388608);         //  8 MB
    unsigned short* Vb  = (unsigned short*)(w + 16777216);        //  8 MB
    unsigned short* Vt  = (unsigned short*)(w + 25165824);        //  8 MB
    unsigned short* xh  = (unsigned short*)(w + 33554432);        //  8 MB
    unsigned short* F   = (unsigned short*)(w + 41943040);        // 16.75 MB (64 MB region)
    unsigned short* Abf = (unsigned short*)(w + 41943040);        // alias: used before feat
    unsigned short* Wbf = (unsigned short*)(w + 109051904);       //  8 MB

    float* out_x    = (float*)d_out;
    float* attn_out = ((float*)d_out) + 4194304;

    cvt_all<<<dim3(8192, 1, 1), 256, 0, stream>>>(query, key, value, Wq, Wk, Wv, Wo,
                                                  Abf, Wbf);
    gemm_qkv<<<dim3(32, 8, 3), 256, 0, stream>>>(Abf, Wbf, bq, bk, bv, Qb, Kb, Vb);
    transpose_v<<<dim3(8, 16, 8), 256, 0, stream>>>(Vb, Vt);
    feat_kernel<<<2048, 256, 0, stream>>>(dist_adj, spk, disc_adj, cooc_adj,
                                          dist_emb, disc_emb, cooc_emb, F);
    attn_kernel<<<dim3(1024, 1, 1), 256, 0, stream>>>(Qb, Kb, Vt, F, maskp, cw, cbp,
                                                      fcw, fcb, attn_out, xh);
    gemm_proj<<<dim3(32, 8), 256, 0, stream>>>(xh, Wbf + 3145728, bo, out_x);
}

// Round 9
// 404.421 us; speedup vs baseline: 1.0147x; 1.0147x over previous
//
#include <hip/hip_runtime.h>

// B=8, S=512, DM=1024, H=16, D=64
using short8 = __attribute__((ext_vector_type(8))) short;
using f32x4  = __attribute__((ext_vector_type(4))) float;
typedef unsigned short u16x4 __attribute__((ext_vector_type(4)));
typedef unsigned short u16x8 __attribute__((ext_vector_type(8)));

__device__ __forceinline__ unsigned short f2bf(float x) {
    union { float f; unsigned u; } v; v.f = x;
    unsigned u = v.u;
    unsigned r = (u + 0x7fffu + ((u >> 16) & 1u)) >> 16;   // RNE
    return (unsigned short)r;
}
__device__ __forceinline__ float bf2f(unsigned short h) {
    union { unsigned u; float f; } v; v.u = ((unsigned)h) << 16;
    return v.f;
}

__device__ __forceinline__ void async16(const void* g, void* l) {
    __builtin_amdgcn_global_load_lds(
        (const __attribute__((address_space(1))) void*)g,
        (__attribute__((address_space(3))) void*)l, 16, 0, 0);
}

// swizzled LDS b128 read: byte = row*stride + (colbyte ^ ((row&7)<<4))
__device__ __forceinline__ short8 lds_swz8(const unsigned short* base, int row,
                                           int colbyte, int stride) {
    const char* p = (const char*)base + row * stride + (colbyte ^ ((row & 7) << 4));
    return *(const short8*)p;
}

// ---------------------------------------------------------------------------
// fp32 -> bf16 converter, QKV (3x4M) + weights (4x1M) in one launch
// ---------------------------------------------------------------------------
__global__ __launch_bounds__(256) void cvt_all(
    const float* __restrict__ q, const float* __restrict__ k, const float* __restrict__ v,
    const float* __restrict__ wq, const float* __restrict__ wk,
    const float* __restrict__ wv, const float* __restrict__ wo,
    unsigned short* __restrict__ dstA, unsigned short* __restrict__ dstW)
{
    int bx = blockIdx.x;
    const float* src;
    unsigned short* o;
    size_t i;
    if (bx < 6144) {
        int z = bx >> 11;
        src = (z == 0) ? q : ((z == 1) ? k : v);
        o = dstA + (size_t)z * 4194304;
        i = ((size_t)(bx & 2047) * 256 + threadIdx.x) * 8;
    } else {
        int z = (bx - 6144) >> 9;
        src = (z == 0) ? wq : ((z == 1) ? wk : ((z == 2) ? wv : wo));
        o = dstW + (size_t)z * 1048576;
        i = ((size_t)((bx - 6144) & 511) * 256 + threadIdx.x) * 8;
    }
    float4 a = *(const float4*)(src + i);
    float4 b = *(const float4*)(src + i + 4);
    ushort4 lo, hi;
    lo.x = f2bf(a.x); lo.y = f2bf(a.y); lo.z = f2bf(a.z); lo.w = f2bf(a.w);
    hi.x = f2bf(b.x); hi.y = f2bf(b.y); hi.z = f2bf(b.z); hi.w = f2bf(b.w);
    *(ushort4*)(o + i) = lo;
    *(ushort4*)(o + i + 4) = hi;
}

// ---------------------------------------------------------------------------
// feature precompute: F[b][q>>2][k][r][f] = {dist,spk,disc,cooc}  (bf16)
// Raw 4-feature store (16.75 MB); per-head 1x1 conv folded into attn.
// ---------------------------------------------------------------------------
__global__ __launch_bounds__(256) void feat_kernel(
    const int* __restrict__ dist_adj, const float* __restrict__ spk,
    const int* __restrict__ disc_adj, const int* __restrict__ cooc_adj,
    const float* __restrict__ dist_emb, const float* __restrict__ disc_emb,
    const float* __restrict__ cooc_emb, unsigned short* __restrict__ F)
{
    __shared__ float s_dist[1023];
    __shared__ float s_disc[17];
    __shared__ float s_cooc[6];
    int tid = threadIdx.x;
    for (int i = tid; i < 1023; i += 256) s_dist[i] = dist_emb[i];
    if (tid < 17) s_disc[tid] = disc_emb[tid];
    if (tid < 6)  s_cooc[tid] = cooc_emb[tid];
    __syncthreads();

    // 2048 blocks: bx = b(3b) | qq(7b) | khalf(1b)
    int bx = blockIdx.x;
    int k  = (bx & 1) * 256 + tid;
    int qq = (bx >> 1) & 127;
    int b  = bx >> 8;

    size_t abase = ((size_t)b * 512 + qq * 4) * 512 + k;
    u16x8 oA, oB;
#pragma unroll
    for (int r = 0; r < 4; ++r) {
        size_t a = abase + (size_t)r * 512;
        int dd   = __builtin_nontemporal_load(dist_adj + a);
        float sp = __builtin_nontemporal_load(spk + a);
        int dc   = __builtin_nontemporal_load(disc_adj + a);
        int cc   = __builtin_nontemporal_load(cooc_adj + a);
        unsigned short f0 = f2bf(s_dist[dd]);
        unsigned short f1 = f2bf(sp);
        unsigned short f2 = f2bf(dc ? s_disc[dc] : 0.f);
        unsigned short f3 = f2bf(cc ? s_cooc[cc] : 0.f);
        if (r < 2) {
            oA[r * 4 + 0] = f0; oA[r * 4 + 1] = f1; oA[r * 4 + 2] = f2; oA[r * 4 + 3] = f3;
        } else {
            oB[(r - 2) * 4 + 0] = f0; oB[(r - 2) * 4 + 1] = f1;
            oB[(r - 2) * 4 + 2] = f2; oB[(r - 2) * 4 + 3] = f3;
        }
    }
    // cached stores: attn re-reads 16x (per-XCD F slice 2.1 MB -> L2-resident)
    unsigned short* fb = F + (((size_t)b * 128 + qq) * 512 + k) * 16;
    *(u16x8*)(fb)     = oA;
    *(u16x8*)(fb + 8) = oB;
}

// ---------------------------------------------------------------------------
// bf16 GEMM, m97 structure: C[m,n] = sum_k A[m,k]*W[n,k] + bias[n]
// OMODE 0: bf16 split-head [b,h,s,d]; OMODE 1: fp32 [m][1024]
// ---------------------------------------------------------------------------
template<int OMODE>
__device__ __forceinline__ void gemm_bf16_body(
    const unsigned short* __restrict__ A, const unsigned short* __restrict__ W,
    const float* __restrict__ bias, void* __restrict__ outp, int m0, int n0)
{
    __shared__ __align__(16) unsigned short As[128 * 32];   // row-major, NO pad
    __shared__ __align__(16) unsigned short Bs[128 * 32];
    int tid = threadIdx.x;
    int lane = tid & 63, wid = tid >> 6;
    int wx = wid & 1, wy = wid >> 1;
    int lanelo = lane & 15, hi8 = (lane >> 4) * 8;
    int rowc = lane >> 2;          // row within 16-row chunk
    int colc = (lane & 3) * 8;     // k-offset (elems) within row

    f32x4 acc[4][4];
#pragma unroll
    for (int i = 0; i < 4; ++i)
#pragma unroll
        for (int j = 0; j < 4; ++j) {
            acc[i][j][0] = 0.f; acc[i][j][1] = 0.f; acc[i][j][2] = 0.f; acc[i][j][3] = 0.f;
        }

    for (int kk = 0; kk < 32; ++kk) {
        int k0 = kk * 32;
        __syncthreads();
#pragma unroll
        for (int p = 0; p < 2; ++p) {
            int c = 2 * wid + p;           // chunk 0..7
            int row = c * 16 + rowc;
            async16(A + (size_t)(m0 + row) * 1024 + k0 + colc, As + c * 512);
        }
#pragma unroll
        for (int p = 0; p < 2; ++p) {
            int c = 2 * wid + p;
            int row = c * 16 + rowc;
            async16(W + (size_t)(n0 + row) * 1024 + k0 + colc, Bs + c * 512);
        }
        __syncthreads();

        short8 af[4], bfr[4];
#pragma unroll
        for (int i = 0; i < 4; ++i)
            af[i] = *(const short8*)(As + (wy*64 + i*16 + lanelo) * 32 + hi8);
#pragma unroll
        for (int j = 0; j < 4; ++j)
            bfr[j] = *(const short8*)(Bs + (wx*64 + j*16 + lanelo) * 32 + hi8);
#pragma unroll
        for (int i = 0; i < 4; ++i)
#pragma unroll
            for (int j = 0; j < 4; ++j)
                acc[i][j] = __builtin_amdgcn_mfma_f32_16x16x32_bf16(af[i], bfr[j], acc[i][j], 0, 0, 0);
    }

    float bia[4];
#pragma unroll
    for (int j = 0; j < 4; ++j) bia[j] = bias[n0 + wx*64 + j*16 + lanelo];
#pragma unroll
    for (int i = 0; i < 4; ++i) {
        int mbase = m0 + wy*64 + i*16 + (lane >> 4) * 4;
#pragma unroll
        for (int j = 0; j < 4; ++j) {
            int n = n0 + wx*64 + j*16 + lanelo;
#pragma unroll
            for (int r = 0; r < 4; ++r) {
                int m = mbase + r;
                float val = acc[i][j][r] + bia[j];
                if (OMODE == 0) {
                    unsigned short* o = (unsigned short*)outp;
                    o[((size_t)((m >> 9) * 16 + (n >> 6)) * 512 + (m & 511)) * 64 + (n & 63)] = f2bf(val);
                } else {
                    float* o = (float*)outp;
                    o[(size_t)m * 1024 + n] = val;
                }
            }
        }
    }
}

// grid (32, 8, 3): x = m-tile, y = n-tile, z = tensor
__global__ __launch_bounds__(256) void gemm_qkv(
    const unsigned short* __restrict__ Abf, const unsigned short* __restrict__ Wbf,
    const float* __restrict__ bq, const float* __restrict__ bk, const float* __restrict__ bv,
    unsigned short* Qb, unsigned short* Kb, unsigned short* Vb)
{
    int z = blockIdx.z;
    const unsigned short* A = Abf + (size_t)z * 4194304;
    const unsigned short* W = Wbf + (size_t)z * 1048576;
    const float* bias = (z == 0) ? bq : ((z == 1) ? bk : bv);
    unsigned short* o = (z == 0) ? Qb : ((z == 1) ? Kb : Vb);
    gemm_bf16_body<0>(A, W, bias, o, blockIdx.x * 128, blockIdx.y * 128);
}

__global__ __launch_bounds__(256) void gemm_proj(
    const unsigned short* __restrict__ xh, const unsigned short* __restrict__ Wo,
    const float* __restrict__ bo, float* __restrict__ out)
{
    gemm_bf16_body<1>(xh, Wo, bo, out, blockIdx.x * 128, blockIdx.y * 128);
}

// ---------------------------------------------------------------------------
// Transpose V: [b,h,s,d] bf16 -> Vt [b,h,d,s] bf16 (coalesced both sides)
// ---------------------------------------------------------------------------
__global__ __launch_bounds__(256) void transpose_v(const unsigned short* __restrict__ Vb,
                                                   unsigned short* __restrict__ Vt)
{
    __shared__ __align__(16) unsigned short T[64][72];
    int tid = threadIdx.x;
    int s0 = blockIdx.x * 64;
    int bh = blockIdx.z * 16 + blockIdx.y;
#pragma unroll
    for (int p = 0; p < 2; ++p) {
        int c = p * 256 + tid;
        int row = c >> 3, kc = (c & 7) * 8;
        uint4 v = *(const uint4*)(Vb + ((size_t)bh * 512 + s0 + row) * 64 + kc);
        *(uint4*)&T[row][kc] = v;
    }
    __syncthreads();
#pragma unroll
    for (int p = 0; p < 2; ++p) {
        int c = p * 256 + tid;
        int d = c >> 3, sc = (c & 7) * 8;
        unsigned vv[4];
#pragma unroll
        for (int i = 0; i < 4; ++i) {
            unsigned lo = T[sc + 2*i][d];
            unsigned hi = T[sc + 2*i + 1][d];
            vv[i] = lo | (hi << 16);
        }
        uint4 o; o.x = vv[0]; o.y = vv[1]; o.z = vv[2]; o.w = vv[3];
        *(uint4*)(Vt + ((size_t)bh * 64 + d) * 512 + s0 + sc) = o;
    }
}

// ---------------------------------------------------------------------------
// Attention. F loaded with clamped 1-j lookahead (16 VGPR live, NOT the
// kt-wide 64-VGPR prefetch that spilled P in R8); per-head conv folded in.
// LDS arena (35840 B):
//   phase1: Qs[64][64]swz @0 (8K), Ks[128][64]swz @8192 (16K)
//   phase3: Vs[64][128]swz @0 (16K), Ps[4][16][136] @16384 (17408)
//   s_mask @33792 (2048)
// ---------------------------------------------------------------------------
__global__ __launch_bounds__(256, 2) void attn_kernel(
    const unsigned short* __restrict__ Qb, const unsigned short* __restrict__ Kb,
    const unsigned short* __restrict__ Vt, const unsigned short* __restrict__ F,
    const int* __restrict__ mask, const float* __restrict__ cw,
    const float* __restrict__ cb, const float* __restrict__ fcw,
    const float* __restrict__ fcb, float* __restrict__ attn_out,
    unsigned short* __restrict__ xh)
{
    __shared__ __align__(16) char smem[35840];
    unsigned short* Qs = (unsigned short*)smem;             // [64][64] swz
    unsigned short* Ks = (unsigned short*)(smem + 8192);    // [128][64] swz
    unsigned short* Vs = (unsigned short*)smem;             // [64][128] swz (phase3)
    unsigned short* Ps = (unsigned short*)(smem + 16384);   // [4][16][136]
    int* s_mask = (int*)(smem + 33792);

    int tid = threadIdx.x;
    int lane = tid & 63, w = tid >> 6;
    int lanelo = lane & 15, hi8 = (lane >> 4) * 8;
    int hi2 = lane >> 4;

    // XCD-aware decomposition: lin%8 = XCD; each XCD owns one b (16 heads)
    int lin = blockIdx.x;
    int xcd = lin & 7;
    int s   = lin >> 3;                 // 0..127
    int bh  = xcd * 16 + (s >> 3);
    int qt  = s & 7;
    int b   = bh >> 4, h = bh & 15;

    float qs  = cw[0] * 0.125f;
    float cw1 = cw[1];
    float cbv = cb[0];
    float w0 = fcw[h * 4 + 0], w1 = fcw[h * 4 + 1];
    float w2 = fcw[h * 4 + 2], w3 = fcw[h * 4 + 3];
    float fcb_h = fcb[h];

    s_mask[tid]       = mask[b * 512 + tid];
    s_mask[tid + 256] = mask[b * 512 + tid + 256];

    // ---- stage Q (8KB, swizzled source) ----
    int r8  = lane >> 3;                 // row within 8-row block
    int gs8 = (lane & 7) ^ r8;           // pre-swizzled 16B slot (128B rows)
#pragma unroll
    for (int p = 0; p < 2; ++p) {
        int row = p * 32 + w * 8 + r8;
        async16(Qb + ((size_t)bh * 512 + qt * 64 + row) * 64 + gs8 * 8,
                Qs + (p * 32 + w * 8) * 64);
    }
    __syncthreads();

    short8 aq[2];
    aq[0] = lds_swz8(Qs, w * 16 + lanelo, hi8 * 2, 128);
    aq[1] = lds_swz8(Qs, w * 16 + lanelo, 64 + hi8 * 2, 128);
    int qrow = qt * 64 + w * 16 + hi2 * 4;
    int qq   = qt * 16 + w * 4 + hi2;                 // q >> 2 for this lane's rows
    // F base for this lane's q-quad: ushort offset ((b*128+qq)*512 + k)*16
    const unsigned short* fbase = F + ((size_t)b * 128 + qq) * 512 * 16;

    float P[32][4];
#pragma unroll
    for (int kt = 0; kt < 4; ++kt) {
        // j=0's F (2x16B), issued before the staging barrier (hides under K stage)
        const unsigned short* f0p = fbase + (size_t)(kt * 8 * 16 + lanelo) * 16;
        u16x8 fA = *(const u16x8*)(f0p);
        u16x8 fB = *(const u16x8*)(f0p + 8);
        __syncthreads();                 // WAR: prev Ks reads done
        // ---- stage K tile (16KB, swizzled source) ----
#pragma unroll
        for (int p = 0; p < 4; ++p) {
            int row = p * 32 + w * 8 + r8;
            async16(Kb + ((size_t)bh * 512 + kt * 128 + row) * 64 + gs8 * 8,
                    Ks + (p * 32 + w * 8) * 64);
        }
        __syncthreads();
#pragma unroll
        for (int j = 0; j < 8; ++j) {
            // clamped 1-j lookahead (j=7 reloads itself: defined, L2-hit)
            int jn = (j < 7) ? j + 1 : 7;
            const unsigned short* fp = fbase + (size_t)((kt * 8 + jn) * 16 + lanelo) * 16;
            u16x8 fAn = *(const u16x8*)(fp);
            u16x8 fBn = *(const u16x8*)(fp + 8);
            short8 b0 = lds_swz8(Ks, j * 16 + lanelo, hi8 * 2, 128);
            short8 b1 = lds_swz8(Ks, j * 16 + lanelo, 64 + hi8 * 2, 128);
            f32x4 acc; acc[0] = 0.f; acc[1] = 0.f; acc[2] = 0.f; acc[3] = 0.f;
            acc = __builtin_amdgcn_mfma_f32_16x16x32_bf16(aq[0], b0, acc, 0, 0, 0);
            acc = __builtin_amdgcn_mfma_f32_16x16x32_bf16(aq[1], b1, acc, 0, 0, 0);
            int jj = kt * 8 + j;
            int kcol = jj * 16 + lanelo;
            int mk = s_mask[kcol];
#pragma unroll
            for (int r = 0; r < 4; ++r) {
                unsigned short e0, e1, e2, e3;
                if (r < 2) {
                    e0 = (unsigned short)fA[r*4+0]; e1 = (unsigned short)fA[r*4+1];
                    e2 = (unsigned short)fA[r*4+2]; e3 = (unsigned short)fA[r*4+3];
                } else {
                    e0 = (unsigned short)fB[(r-2)*4+0]; e1 = (unsigned short)fB[(r-2)*4+1];
                    e2 = (unsigned short)fB[(r-2)*4+2]; e3 = (unsigned short)fB[(r-2)*4+3];
                }
                float dot = w0 * bf2f(e0) + w1 * bf2f(e1) + w2 * bf2f(e2)
                          + w3 * bf2f(e3) + fcb_h;
                float gh = fmaxf(dot, 0.f) * cw1;
                float e = qs * acc[r] + gh + cbv;
                e = fmaxf(e, 0.f);
                P[jj][r] = mk ? __expf(e) : 0.f;
            }
            fA = fAn; fB = fBn;
        }
    }

    float inv[4];
#pragma unroll
    for (int r = 0; r < 4; ++r) {
        float s0 = 0.f;
#pragma unroll
        for (int jj = 0; jj < 32; ++jj) s0 += P[jj][r];
        s0 += __shfl_xor(s0, 1, 64);
        s0 += __shfl_xor(s0, 2, 64);
        s0 += __shfl_xor(s0, 4, 64);
        s0 += __shfl_xor(s0, 8, 64);
        inv[r] = 1.0f / s0;
    }

    // normalized P -> attn_out: scalar nt stores (16-lane group = 64B segment)
    {
        float* ap = attn_out + ((size_t)bh * 512 + qrow) * 512 + lanelo;
#pragma unroll
        for (int jj = 0; jj < 32; ++jj)
#pragma unroll
            for (int r = 0; r < 4; ++r)
                __builtin_nontemporal_store(P[jj][r] * inv[r],
                                            ap + (size_t)r * 512 + jj * 16);
    }

    // ---- PV in 4 chunks of K=128 ----
    f32x4 xacc[4];
#pragma unroll
    for (int jf = 0; jf < 4; ++jf) { xacc[jf][0]=0.f; xacc[jf][1]=0.f; xacc[jf][2]=0.f; xacc[jf][3]=0.f; }

    int r8v  = ((w & 1) * 4 + hi2) & 7;        // Vs row&7 for this lane's stage row
    int gs16 = (lane & 15) ^ r8v;              // pre-swizzled 16B slot (256B rows)
    unsigned short* Psw = Ps + w * 16 * 136;
#pragma unroll
    for (int c = 0; c < 4; ++c) {
        __syncthreads();                       // WAR (c=0: Qs/Ks dead; else prev reads)
        // stage Vt[:, c*128 +: 128] (16KB, swizzled source)
#pragma unroll
        for (int p = 0; p < 4; ++p) {
            int row = p * 16 + w * 4 + hi2;
            async16(Vt + ((size_t)bh * 64 + row) * 512 + c * 128 + gs16 * 8,
                    Vs + (p * 16 + w * 4) * 128);
        }
        // transpose this chunk of P into Ps (per-wave region)
#pragma unroll
        for (int jc = 0; jc < 8; ++jc) {
            int jj = c * 8 + jc;
#pragma unroll
            for (int r = 0; r < 4; ++r)
                Psw[(hi2 * 4 + r) * 136 + jc * 16 + lanelo] = f2bf(P[jj][r]);
        }
        __syncthreads();
#pragma unroll
        for (int ksub = 0; ksub < 4; ++ksub) {
            short8 ap8 = *(const short8*)(Psw + (size_t)lanelo * 136 + ksub * 32 + hi8);
#pragma unroll
            for (int jf = 0; jf < 4; ++jf) {
                short8 bv = lds_swz8(Vs, jf * 16 + lanelo, ksub * 64 + hi8 * 2, 256);
                xacc[jf] = __builtin_amdgcn_mfma_f32_16x16x32_bf16(ap8, bv, xacc[jf], 0, 0, 0);
            }
        }
    }

#pragma unroll
    for (int jf = 0; jf < 4; ++jf) {
        int d = jf * 16 + lanelo;
#pragma unroll
        for (int r = 0; r < 4; ++r) {
            float val = xacc[jf][r] * inv[r];
            xh[((size_t)b * 512 + qrow + r) * 1024 + h * 64 + d] = f2bf(val);
        }
    }
}

// ---------------------------------------------------------------------------
extern "C" void kernel_launch(void* const* d_in, const int* in_sizes, int n_in,
                              void* d_out, int out_size, void* d_ws, size_t ws_size,
                              hipStream_t stream) {
    (void)in_sizes; (void)n_in; (void)out_size; (void)ws_size;
    const float* query    = (const float*)d_in[0];
    const float* key      = (const float*)d_in[1];
    const float* value    = (const float*)d_in[2];
    const int*   dist_adj = (const int*)d_in[3];
    const float* spk      = (const float*)d_in[4];
    const int*   disc_adj = (const int*)d_in[5];
    const int*   cooc_adj = (const int*)d_in[6];
    const int*   maskp    = (const int*)d_in[7];
    const float* Wq = (const float*)d_in[8];  const float* bq = (const float*)d_in[9];
    const float* Wk = (const float*)d_in[10]; const float* bk = (const float*)d_in[11];
    const float* Wv = (const float*)d_in[12]; const float* bv = (const float*)d_in[13];
    const float* Wo = (const float*)d_in[14]; const float* bo = (const float*)d_in[15];
    const float* dist_emb = (const float*)d_in[16];
    const float* disc_emb = (const float*)d_in[17];
    const float* cooc_emb = (const float*)d_in[18];
    const float* fcw = (const float*)d_in[19];
    const float* fcb = (const float*)d_in[20];
    const float* cw  = (const float*)d_in[21];
    const float* cbp = (const float*)d_in[22];

    char* w = (char*)d_ws;
    unsigned short* Qb  = (unsigned short*)(w);                   //  8 MB
    unsigned short* Kb  = (unsigned short*)(w + 8388608);         //  8 MB
    unsigned short* Vb  = (unsigned short*)(w + 16777216);        //  8 MB
    unsigned short* Vt  = (unsigned short*)(w + 25165824);        //  8 MB
    unsigned short* xh  = (unsigned short*)(w + 33554432);        //  8 MB
    unsigned short* F   = (unsigned short*)(w + 41943040);        // 16.75 MB (64 MB region)
    unsigned short* Abf = (unsigned short*)(w + 41943040);        // alias: used before feat
    unsigned short* Wbf = (unsigned short*)(w + 109051904);       //  8 MB

    float* out_x    = (float*)d_out;
    float* attn_out = ((float*)d_out) + 4194304;

    cvt_all<<<dim3(8192, 1, 1), 256, 0, stream>>>(query, key, value, Wq, Wk, Wv, Wo,
                                                  Abf, Wbf);
    gemm_qkv<<<dim3(32, 8, 3), 256, 0, stream>>>(Abf, Wbf, bq, bk, bv, Qb, Kb, Vb);
    transpose_v<<<dim3(8, 16, 8), 256, 0, stream>>>(Vb, Vt);
    feat_kernel<<<2048, 256, 0, stream>>>(dist_adj, spk, disc_adj, cooc_adj,
                                          dist_emb, disc_emb, cooc_emb, F);
    attn_kernel<<<dim3(1024, 1, 1), 256, 0, stream>>>(Qb, Kb, Vt, F, maskp, cw, cbp,
                                                      fcw, fcb, attn_out, xh);
    gemm_proj<<<dim3(32, 8), 256, 0, stream>>>(xh, Wbf + 3145728, bo, out_x);
}

// Round 10
// 374.631 us; speedup vs baseline: 1.0954x; 1.0795x over previous
//
#include <hip/hip_runtime.h>

// B=8, S=512, DM=1024, H=16, D=64
using short8 = __attribute__((ext_vector_type(8))) short;
using f32x4  = __attribute__((ext_vector_type(4))) float;
typedef unsigned short u16x4 __attribute__((ext_vector_type(4)));
typedef unsigned short u16x8 __attribute__((ext_vector_type(8)));

__device__ __forceinline__ unsigned short f2bf(float x) {
    union { float f; unsigned u; } v; v.f = x;
    unsigned u = v.u;
    unsigned r = (u + 0x7fffu + ((u >> 16) & 1u)) >> 16;   // RNE
    return (unsigned short)r;
}
__device__ __forceinline__ float bf2f(unsigned short h) {
    union { unsigned u; float f; } v; v.u = ((unsigned)h) << 16;
    return v.f;
}

__device__ __forceinline__ void async16(const void* g, void* l) {
    __builtin_amdgcn_global_load_lds(
        (const __attribute__((address_space(1))) void*)g,
        (__attribute__((address_space(3))) void*)l, 16, 0, 0);
}

// swizzled LDS b128 read: byte = row*stride + (colbyte ^ ((row&7)<<4))
__device__ __forceinline__ short8 lds_swz8(const unsigned short* base, int row,
                                           int colbyte, int stride) {
    const char* p = (const char*)base + row * stride + (colbyte ^ ((row & 7) << 4));
    return *(const short8*)p;
}

// ---------------------------------------------------------------------------
// fp32 -> bf16 converter, QKV (3x4M) + weights (4x1M) in one launch
// ---------------------------------------------------------------------------
__global__ __launch_bounds__(256) void cvt_all(
    const float* __restrict__ q, const float* __restrict__ k, const float* __restrict__ v,
    const float* __restrict__ wq, const float* __restrict__ wk,
    const float* __restrict__ wv, const float* __restrict__ wo,
    unsigned short* __restrict__ dstA, unsigned short* __restrict__ dstW)
{
    int bx = blockIdx.x;
    const float* src;
    unsigned short* o;
    size_t i;
    if (bx < 6144) {
        int z = bx >> 11;
        src = (z == 0) ? q : ((z == 1) ? k : v);
        o = dstA + (size_t)z * 4194304;
        i = ((size_t)(bx & 2047) * 256 + threadIdx.x) * 8;
    } else {
        int z = (bx - 6144) >> 9;
        src = (z == 0) ? wq : ((z == 1) ? wk : ((z == 2) ? wv : wo));
        o = dstW + (size_t)z * 1048576;
        i = ((size_t)((bx - 6144) & 511) * 256 + threadIdx.x) * 8;
    }
    float4 a = *(const float4*)(src + i);
    float4 b = *(const float4*)(src + i + 4);
    ushort4 lo, hi;
    lo.x = f2bf(a.x); lo.y = f2bf(a.y); lo.z = f2bf(a.z); lo.w = f2bf(a.w);
    hi.x = f2bf(b.x); hi.y = f2bf(b.y); hi.z = f2bf(b.z); hi.w = f2bf(b.w);
    *(ushort4*)(o + i) = lo;
    *(ushort4*)(o + i + 4) = hi;
}

// ---------------------------------------------------------------------------
// feature precompute: F[b][q>>2][k][r][f] = {dist,spk,disc,cooc}  (bf16)
// Raw 4-feature store (16.75 MB); per-head 1x1 conv folded into attn.
// ---------------------------------------------------------------------------
__global__ __launch_bounds__(256) void feat_kernel(
    const int* __restrict__ dist_adj, const float* __restrict__ spk,
    const int* __restrict__ disc_adj, const int* __restrict__ cooc_adj,
    const float* __restrict__ dist_emb, const float* __restrict__ disc_emb,
    const float* __restrict__ cooc_emb, unsigned short* __restrict__ F)
{
    __shared__ float s_dist[1023];
    __shared__ float s_disc[17];
    __shared__ float s_cooc[6];
    int tid = threadIdx.x;
    for (int i = tid; i < 1023; i += 256) s_dist[i] = dist_emb[i];
    if (tid < 17) s_disc[tid] = disc_emb[tid];
    if (tid < 6)  s_cooc[tid] = cooc_emb[tid];
    __syncthreads();

    // 2048 blocks: bx = b(3b) | qq(7b) | khalf(1b)
    int bx = blockIdx.x;
    int k  = (bx & 1) * 256 + tid;
    int qq = (bx >> 1) & 127;
    int b  = bx >> 8;

    size_t abase = ((size_t)b * 512 + qq * 4) * 512 + k;
    u16x8 oA, oB;
#pragma unroll
    for (int r = 0; r < 4; ++r) {
        size_t a = abase + (size_t)r * 512;
        int dd   = __builtin_nontemporal_load(dist_adj + a);
        float sp = __builtin_nontemporal_load(spk + a);
        int dc   = __builtin_nontemporal_load(disc_adj + a);
        int cc   = __builtin_nontemporal_load(cooc_adj + a);
        unsigned short f0 = f2bf(s_dist[dd]);
        unsigned short f1 = f2bf(sp);
        unsigned short f2 = f2bf(dc ? s_disc[dc] : 0.f);
        unsigned short f3 = f2bf(cc ? s_cooc[cc] : 0.f);
        if (r < 2) {
            oA[r * 4 + 0] = f0; oA[r * 4 + 1] = f1; oA[r * 4 + 2] = f2; oA[r * 4 + 3] = f3;
        } else {
            oB[(r - 2) * 4 + 0] = f0; oB[(r - 2) * 4 + 1] = f1;
            oB[(r - 2) * 4 + 2] = f2; oB[(r - 2) * 4 + 3] = f3;
        }
    }
    // cached stores: attn re-reads (per-XCD F slice 2.1 MB -> L2-resident)
    unsigned short* fb = F + (((size_t)b * 128 + qq) * 512 + k) * 16;
    *(u16x8*)(fb)     = oA;
    *(u16x8*)(fb + 8) = oB;
}

// ---------------------------------------------------------------------------
// bf16 GEMM, m97 structure: C[m,n] = sum_k A[m,k]*W[n,k] + bias[n]
// OMODE 0: bf16 split-head [b,h,s,d]; OMODE 1: fp32 [m][1024]
// ---------------------------------------------------------------------------
template<int OMODE>
__device__ __forceinline__ void gemm_bf16_body(
    const unsigned short* __restrict__ A, const unsigned short* __restrict__ W,
    const float* __restrict__ bias, void* __restrict__ outp, int m0, int n0)
{
    __shared__ __align__(16) unsigned short As[128 * 32];   // row-major, NO pad
    __shared__ __align__(16) unsigned short Bs[128 * 32];
    int tid = threadIdx.x;
    int lane = tid & 63, wid = tid >> 6;
    int wx = wid & 1, wy = wid >> 1;
    int lanelo = lane & 15, hi8 = (lane >> 4) * 8;
    int rowc = lane >> 2;          // row within 16-row chunk
    int colc = (lane & 3) * 8;     // k-offset (elems) within row

    f32x4 acc[4][4];
#pragma unroll
    for (int i = 0; i < 4; ++i)
#pragma unroll
        for (int j = 0; j < 4; ++j) {
            acc[i][j][0] = 0.f; acc[i][j][1] = 0.f; acc[i][j][2] = 0.f; acc[i][j][3] = 0.f;
        }

    for (int kk = 0; kk < 32; ++kk) {
        int k0 = kk * 32;
        __syncthreads();
#pragma unroll
        for (int p = 0; p < 2; ++p) {
            int c = 2 * wid + p;           // chunk 0..7
            int row = c * 16 + rowc;
            async16(A + (size_t)(m0 + row) * 1024 + k0 + colc, As + c * 512);
        }
#pragma unroll
        for (int p = 0; p < 2; ++p) {
            int c = 2 * wid + p;
            int row = c * 16 + rowc;
            async16(W + (size_t)(n0 + row) * 1024 + k0 + colc, Bs + c * 512);
        }
        __syncthreads();

        short8 af[4], bfr[4];
#pragma unroll
        for (int i = 0; i < 4; ++i)
            af[i] = *(const short8*)(As + (wy*64 + i*16 + lanelo) * 32 + hi8);
#pragma unroll
        for (int j = 0; j < 4; ++j)
            bfr[j] = *(const short8*)(Bs + (wx*64 + j*16 + lanelo) * 32 + hi8);
#pragma unroll
        for (int i = 0; i < 4; ++i)
#pragma unroll
            for (int j = 0; j < 4; ++j)
                acc[i][j] = __builtin_amdgcn_mfma_f32_16x16x32_bf16(af[i], bfr[j], acc[i][j], 0, 0, 0);
    }

    float bia[4];
#pragma unroll
    for (int j = 0; j < 4; ++j) bia[j] = bias[n0 + wx*64 + j*16 + lanelo];
#pragma unroll
    for (int i = 0; i < 4; ++i) {
        int mbase = m0 + wy*64 + i*16 + (lane >> 4) * 4;
#pragma unroll
        for (int j = 0; j < 4; ++j) {
            int n = n0 + wx*64 + j*16 + lanelo;
#pragma unroll
            for (int r = 0; r < 4; ++r) {
                int m = mbase + r;
                float val = acc[i][j][r] + bia[j];
                if (OMODE == 0) {
                    unsigned short* o = (unsigned short*)outp;
                    o[((size_t)((m >> 9) * 16 + (n >> 6)) * 512 + (m & 511)) * 64 + (n & 63)] = f2bf(val);
                } else {
                    float* o = (float*)outp;
                    o[(size_t)m * 1024 + n] = val;
                }
            }
        }
    }
}

// grid (32, 8, 3): x = m-tile, y = n-tile, z = tensor
__global__ __launch_bounds__(256) void gemm_qkv(
    const unsigned short* __restrict__ Abf, const unsigned short* __restrict__ Wbf,
    const float* __restrict__ bq, const float* __restrict__ bk, const float* __restrict__ bv,
    unsigned short* Qb, unsigned short* Kb, unsigned short* Vb)
{
    int z = blockIdx.z;
    const unsigned short* A = Abf + (size_t)z * 4194304;
    const unsigned short* W = Wbf + (size_t)z * 1048576;
    const float* bias = (z == 0) ? bq : ((z == 1) ? bk : bv);
    unsigned short* o = (z == 0) ? Qb : ((z == 1) ? Kb : Vb);
    gemm_bf16_body<0>(A, W, bias, o, blockIdx.x * 128, blockIdx.y * 128);
}

__global__ __launch_bounds__(256) void gemm_proj(
    const unsigned short* __restrict__ xh, const unsigned short* __restrict__ Wo,
    const float* __restrict__ bo, float* __restrict__ out)
{
    gemm_bf16_body<1>(xh, Wo, bo, out, blockIdx.x * 128, blockIdx.y * 128);
}

// ---------------------------------------------------------------------------
// Transpose V: [b,h,s,d] bf16 -> Vt [b,h,d,s] bf16 (coalesced both sides)
// ---------------------------------------------------------------------------
__global__ __launch_bounds__(256) void transpose_v(const unsigned short* __restrict__ Vb,
                                                   unsigned short* __restrict__ Vt)
{
    __shared__ __align__(16) unsigned short T[64][72];
    int tid = threadIdx.x;
    int s0 = blockIdx.x * 64;
    int bh = blockIdx.z * 16 + blockIdx.y;
#pragma unroll
    for (int p = 0; p < 2; ++p) {
        int c = p * 256 + tid;
        int row = c >> 3, kc = (c & 7) * 8;
        uint4 v = *(const uint4*)(Vb + ((size_t)bh * 512 + s0 + row) * 64 + kc);
        *(uint4*)&T[row][kc] = v;
    }
    __syncthreads();
#pragma unroll
    for (int p = 0; p < 2; ++p) {
        int c = p * 256 + tid;
        int d = c >> 3, sc = (c & 7) * 8;
        unsigned vv[4];
#pragma unroll
        for (int i = 0; i < 4; ++i) {
            unsigned lo = T[sc + 2*i][d];
            unsigned hi = T[sc + 2*i + 1][d];
            vv[i] = lo | (hi << 16);
        }
        uint4 o; o.x = vv[0]; o.y = vv[1]; o.z = vv[2]; o.w = vv[3];
        *(uint4*)(Vt + ((size_t)bh * 64 + d) * 512 + s0 + sc) = o;
    }
}

// ---------------------------------------------------------------------------
// Attention, 2-PASS (flash-style): P[32][4] is NEVER held in registers.
// Pass 1: QK^T -> row-sums only (4 regs). Pass 2: recompute QK^T (bit-
// identical), normalize with inv, store attn_out + feed PV per 128-k chunk.
// QK MFMA is ~2% util, so recompute is nearly free; K/F re-reads are L2-hot.
// LDS arena (52224 B, 3 blocks/CU):
//   Qs[64][64]swz @0 (8K, prologue; overlaps Ks)
//   Ks[128][64]swz @0 (16K)
//   Vs[64][128]swz @16384 (16K, pass 2)
//   Ps[4][16][136] @32768 (17408, pass 2)
//   s_mask @50176 (2K)
// ---------------------------------------------------------------------------
__global__ __launch_bounds__(256, 2) void attn_kernel(
    const unsigned short* __restrict__ Qb, const unsigned short* __restrict__ Kb,
    const unsigned short* __restrict__ Vt, const unsigned short* __restrict__ F,
    const int* __restrict__ mask, const float* __restrict__ cw,
    const float* __restrict__ cb, const float* __restrict__ fcw,
    const float* __restrict__ fcb, float* __restrict__ attn_out,
    unsigned short* __restrict__ xh)
{
    __shared__ __align__(16) char smem[52224];
    unsigned short* Qs = (unsigned short*)smem;             // [64][64] swz (prologue)
    unsigned short* Ks = (unsigned short*)smem;             // [128][64] swz
    unsigned short* Vs = (unsigned short*)(smem + 16384);   // [64][128] swz
    unsigned short* Ps = (unsigned short*)(smem + 32768);   // [4][16][136]
    int* s_mask = (int*)(smem + 50176);

    int tid = threadIdx.x;
    int lane = tid & 63, w = tid >> 6;
    int lanelo = lane & 15, hi8 = (lane >> 4) * 8;
    int hi2 = lane >> 4;

    // XCD-aware decomposition: lin%8 = XCD; each XCD owns one b (16 heads)
    int lin = blockIdx.x;
    int xcd = lin & 7;
    int s   = lin >> 3;                 // 0..127
    int bh  = xcd * 16 + (s >> 3);
    int qt  = s & 7;
    int b   = bh >> 4, h = bh & 15;

    float qs  = cw[0] * 0.125f;
    float cw1 = cw[1];
    float cbv = cb[0];
    float w0 = fcw[h * 4 + 0], w1 = fcw[h * 4 + 1];
    float w2 = fcw[h * 4 + 2], w3 = fcw[h * 4 + 3];
    float fcb_h = fcb[h];

    s_mask[tid]       = mask[b * 512 + tid];
    s_mask[tid + 256] = mask[b * 512 + tid + 256];

    // ---- stage Q (8KB, swizzled source) ----
    int r8  = lane >> 3;                 // row within 8-row block
    int gs8 = (lane & 7) ^ r8;           // pre-swizzled 16B slot (128B rows)
#pragma unroll
    for (int p = 0; p < 2; ++p) {
        int row = p * 32 + w * 8 + r8;
        async16(Qb + ((size_t)bh * 512 + qt * 64 + row) * 64 + gs8 * 8,
                Qs + (p * 32 + w * 8) * 64);
    }
    __syncthreads();

    short8 aq[2];
    aq[0] = lds_swz8(Qs, w * 16 + lanelo, hi8 * 2, 128);
    aq[1] = lds_swz8(Qs, w * 16 + lanelo, 64 + hi8 * 2, 128);
    int qrow = qt * 64 + w * 16 + hi2 * 4;
    int qq   = qt * 16 + w * 4 + hi2;                 // q >> 2 for this lane's rows
    const unsigned short* fbase = F + ((size_t)b * 128 + qq) * 512 * 16;

    // ================= PASS 1: row sums only =================
    float ssum[4] = {0.f, 0.f, 0.f, 0.f};
#pragma unroll
    for (int kt = 0; kt < 4; ++kt) {
        __syncthreads();                 // WAR: prev Ks reads (or aq reads) done
#pragma unroll
        for (int p = 0; p < 4; ++p) {
            int row = p * 32 + w * 8 + r8;
            async16(Kb + ((size_t)bh * 512 + kt * 128 + row) * 64 + gs8 * 8,
                    Ks + (p * 32 + w * 8) * 64);
        }
        __syncthreads();
#pragma unroll
        for (int j = 0; j < 8; ++j) {
            const unsigned short* fp = fbase + (size_t)((kt * 8 + j) * 16 + lanelo) * 16;
            u16x8 fA = *(const u16x8*)(fp);
            u16x8 fB = *(const u16x8*)(fp + 8);
            short8 b0 = lds_swz8(Ks, j * 16 + lanelo, hi8 * 2, 128);
            short8 b1 = lds_swz8(Ks, j * 16 + lanelo, 64 + hi8 * 2, 128);
            f32x4 acc; acc[0] = 0.f; acc[1] = 0.f; acc[2] = 0.f; acc[3] = 0.f;
            acc = __builtin_amdgcn_mfma_f32_16x16x32_bf16(aq[0], b0, acc, 0, 0, 0);
            acc = __builtin_amdgcn_mfma_f32_16x16x32_bf16(aq[1], b1, acc, 0, 0, 0);
            int mk = s_mask[(kt * 8 + j) * 16 + lanelo];
#pragma unroll
            for (int r = 0; r < 4; ++r) {
                unsigned short e0, e1, e2, e3;
                if (r < 2) {
                    e0 = (unsigned short)fA[r*4+0]; e1 = (unsigned short)fA[r*4+1];
                    e2 = (unsigned short)fA[r*4+2]; e3 = (unsigned short)fA[r*4+3];
                } else {
                    e0 = (unsigned short)fB[(r-2)*4+0]; e1 = (unsigned short)fB[(r-2)*4+1];
                    e2 = (unsigned short)fB[(r-2)*4+2]; e3 = (unsigned short)fB[(r-2)*4+3];
                }
                float dot = w0 * bf2f(e0) + w1 * bf2f(e1) + w2 * bf2f(e2)
                          + w3 * bf2f(e3) + fcb_h;
                float gh = fmaxf(dot, 0.f) * cw1;
                float e = fmaxf(qs * acc[r] + gh + cbv, 0.f);
                ssum[r] += mk ? __expf(e) : 0.f;
            }
        }
    }

    float inv[4];
#pragma unroll
    for (int r = 0; r < 4; ++r) {
        float s0 = ssum[r];
        s0 += __shfl_xor(s0, 1, 64);
        s0 += __shfl_xor(s0, 2, 64);
        s0 += __shfl_xor(s0, 4, 64);
        s0 += __shfl_xor(s0, 8, 64);
        inv[r] = 1.0f / s0;
    }

    // ================= PASS 2: recompute, store, PV =================
    f32x4 xacc[4];
#pragma unroll
    for (int jf = 0; jf < 4; ++jf) { xacc[jf][0]=0.f; xacc[jf][1]=0.f; xacc[jf][2]=0.f; xacc[jf][3]=0.f; }

    int r8v  = ((w & 1) * 4 + hi2) & 7;        // Vs row&7 for this lane's stage row
    int gs16 = (lane & 15) ^ r8v;              // pre-swizzled 16B slot (256B rows)
    unsigned short* Psw = Ps + w * 16 * 136;
    float* ap = attn_out + ((size_t)bh * 512 + qrow) * 512 + lanelo;

#pragma unroll
    for (int kt = 0; kt < 4; ++kt) {
        __syncthreads();                       // WAR: prev Ks/Vs reads done
        // stage K tile (QK recompute) + Vt chunk (PV), both swizzled source
#pragma unroll
        for (int p = 0; p < 4; ++p) {
            int row = p * 32 + w * 8 + r8;
            async16(Kb + ((size_t)bh * 512 + kt * 128 + row) * 64 + gs8 * 8,
                    Ks + (p * 32 + w * 8) * 64);
        }
#pragma unroll
        for (int p = 0; p < 4; ++p) {
            int row = p * 16 + w * 4 + hi2;
            async16(Vt + ((size_t)bh * 64 + row) * 512 + kt * 128 + gs16 * 8,
                    Vs + (p * 16 + w * 4) * 128);
        }
        __syncthreads();
#pragma unroll
        for (int j = 0; j < 8; ++j) {
            const unsigned short* fp = fbase + (size_t)((kt * 8 + j) * 16 + lanelo) * 16;
            u16x8 fA = *(const u16x8*)(fp);
            u16x8 fB = *(const u16x8*)(fp + 8);
            short8 b0 = lds_swz8(Ks, j * 16 + lanelo, hi8 * 2, 128);
            short8 b1 = lds_swz8(Ks, j * 16 + lanelo, 64 + hi8 * 2, 128);
            f32x4 acc; acc[0] = 0.f; acc[1] = 0.f; acc[2] = 0.f; acc[3] = 0.f;
            acc = __builtin_amdgcn_mfma_f32_16x16x32_bf16(aq[0], b0, acc, 0, 0, 0);
            acc = __builtin_amdgcn_mfma_f32_16x16x32_bf16(aq[1], b1, acc, 0, 0, 0);
            int mk = s_mask[(kt * 8 + j) * 16 + lanelo];
#pragma unroll
            for (int r = 0; r < 4; ++r) {
                unsigned short e0, e1, e2, e3;
                if (r < 2) {
                    e0 = (unsigned short)fA[r*4+0]; e1 = (unsigned short)fA[r*4+1];
                    e2 = (unsigned short)fA[r*4+2]; e3 = (unsigned short)fA[r*4+3];
                } else {
                    e0 = (unsigned short)fB[(r-2)*4+0]; e1 = (unsigned short)fB[(r-2)*4+1];
                    e2 = (unsigned short)fB[(r-2)*4+2]; e3 = (unsigned short)fB[(r-2)*4+3];
                }
                float dot = w0 * bf2f(e0) + w1 * bf2f(e1) + w2 * bf2f(e2)
                          + w3 * bf2f(e3) + fcb_h;
                float gh = fmaxf(dot, 0.f) * cw1;
                float e = fmaxf(qs * acc[r] + gh + cbv, 0.f);
                float pn = mk ? __expf(e) * inv[r] : 0.f;   // bit-identical exp, normalized
                __builtin_nontemporal_store(pn, ap + (size_t)r * 512 + (kt * 8 + j) * 16);
                Psw[(hi2 * 4 + r) * 136 + j * 16 + lanelo] = f2bf(pn);
            }
        }
        __syncthreads();                       // Ps/Vs ready for PV
#pragma unroll
        for (int ksub = 0; ksub < 4; ++ksub) {
            short8 ap8 = *(const short8*)(Psw + (size_t)lanelo * 136 + ksub * 32 + hi8);
#pragma unroll
            for (int jf = 0; jf < 4; ++jf) {
                short8 bv = lds_swz8(Vs, jf * 16 + lanelo, ksub * 64 + hi8 * 2, 256);
                xacc[jf] = __builtin_amdgcn_mfma_f32_16x16x32_bf16(ap8, bv, xacc[jf], 0, 0, 0);
            }
        }
    }

    // xh: already normalized (P was normalized before PV)
#pragma unroll
    for (int jf = 0; jf < 4; ++jf) {
        int d = jf * 16 + lanelo;
#pragma unroll
        for (int r = 0; r < 4; ++r)
            xh[((size_t)b * 512 + qrow + r) * 1024 + h * 64 + d] = f2bf(xacc[jf][r]);
    }
}

// ---------------------------------------------------------------------------
extern "C" void kernel_launch(void* const* d_in, const int* in_sizes, int n_in,
                              void* d_out, int out_size, void* d_ws, size_t ws_size,
                              hipStream_t stream) {
    (void)in_sizes; (void)n_in; (void)out_size; (void)ws_size;
    const float* query    = (const float*)d_in[0];
    const float* key      = (const float*)d_in[1];
    const float* value    = (const float*)d_in[2];
    const int*   dist_adj = (const int*)d_in[3];
    const float* spk      = (const float*)d_in[4];
    const int*   disc_adj = (const int*)d_in[5];
    const int*   cooc_adj = (const int*)d_in[6];
    const int*   maskp    = (const int*)d_in[7];
    const float* Wq = (const float*)d_in[8];  const float* bq = (const float*)d_in[9];
    const float* Wk = (const float*)d_in[10]; const float* bk = (const float*)d_in[11];
    const float* Wv = (const float*)d_in[12]; const float* bv = (const float*)d_in[13];
    const float* Wo = (const float*)d_in[14]; const float* bo = (const float*)d_in[15];
    const float* dist_emb = (const float*)d_in[16];
    const float* disc_emb = (const float*)d_in[17];
    const float* cooc_emb = (const float*)d_in[18];
    const float* fcw = (const float*)d_in[19];
    const float* fcb = (const float*)d_in[20];
    const float* cw  = (const float*)d_in[21];
    const float* cbp = (const float*)d_in[22];

    char* w = (char*)d_ws;
    unsigned short* Qb  = (unsigned short*)(w);                   //  8 MB
    unsigned short* Kb  = (unsigned short*)(w + 8388608);         //  8 MB
    unsigned short* Vb  = (unsigned short*)(w + 16777216);        //  8 MB
    unsigned short* Vt  = (unsigned short*)(w + 25165824);        //  8 MB
    unsigned short* xh  = (unsigned short*)(w + 33554432);        //  8 MB
    unsigned short* F   = (unsigned short*)(w + 41943040);        // 16.75 MB (64 MB region)
    unsigned short* Abf = (unsigned short*)(w + 41943040);        // alias: used before feat
    unsigned short* Wbf = (unsigned short*)(w + 109051904);       //  8 MB

    float* out_x    = (float*)d_out;
    float* attn_out = ((float*)d_out) + 4194304;

    cvt_all<<<dim3(8192, 1, 1), 256, 0, stream>>>(query, key, value, Wq, Wk, Wv, Wo,
                                                  Abf, Wbf);
    gemm_qkv<<<dim3(32, 8, 3), 256, 0, stream>>>(Abf, Wbf, bq, bk, bv, Qb, Kb, Vb);
    transpose_v<<<dim3(8, 16, 8), 256, 0, stream>>>(Vb, Vt);
    feat_kernel<<<2048, 256, 0, stream>>>(dist_adj, spk, disc_adj, cooc_adj,
                                          dist_emb, disc_emb, cooc_emb, F);
    attn_kernel<<<dim3(1024, 1, 1), 256, 0, stream>>>(Qb, Kb, Vt, F, maskp, cw, cbp,
                                                      fcw, fcb, attn_out, xh);
    gemm_proj<<<dim3(32, 8), 256, 0, stream>>>(xh, Wbf + 3145728, bo, out_x);
}